// Round 1
// baseline (57.094 us; speedup 1.0000x reference)
//
#include <hip/hip_runtime.h>

// Problem: MinibatchDiscrimination — all-pairs L1 distance + concat.
//   inputs: [N=1024, D=512] fp32
//   out[i, 0:512]        = inputs[i, :]
//   out[i, 512 + j]      = sum_d |x[i,d] - x[j,d]|   (j in 0..1023)
// out is [1024, 1536] fp32, row-major.

#define N_PTS 1024
#define D_DIM 512
#define OUTW  (D_DIM + N_PTS)   // 1536

#define BM 64
#define BN 64
#define BK 64
#define PAD 1                    // +1 pad: staging writes / B-reads <=2-way bank alias (free)

// -------- copy inputs into out[:, 0:D] ------------------------------------
__global__ __launch_bounds__(256) void copy_rows_kernel(const float* __restrict__ x,
                                                        float* __restrict__ out) {
    int idx = blockIdx.x * blockDim.x + threadIdx.x;   // 0 .. N*D/4-1
    int i = idx >> 7;          // D/4 = 128 float4 per row
    int d = idx & 127;
    *(float4*)&out[(size_t)i * OUTW + (d << 2)] =
        *(const float4*)&x[(size_t)i * D_DIM + (d << 2)];
}

// -------- tiled all-pairs L1 ---------------------------------------------
// block 16x16 threads; each thread computes a 4x4 micro-tile of the 64x64
// output tile. LDS tiles stored k-major [BK][BM+1].
__global__ __launch_bounds__(256) void l1_pairs_kernel(const float* __restrict__ x,
                                                       float* __restrict__ out) {
    __shared__ float As[BK][BM + PAD];
    __shared__ float Bs[BK][BN + PAD];

    const int tx = threadIdx.x;        // 0..15 -> j (col) direction
    const int ty = threadIdx.y;        // 0..15 -> i (row) direction
    const int t  = ty * 16 + tx;       // 0..255
    const int lr = t >> 4;             // 0..15: row-in-tile base for staging
    const int lk = (t & 15) << 2;      // 0,4,..,60: k-col (float4) for staging

    const int rowA = blockIdx.y * BM;  // i-tile base
    const int rowB = blockIdx.x * BN;  // j-tile base

    float acc[4][4] = {};

    for (int kb = 0; kb < D_DIM; kb += BK) {
        // ---- stage A (rows rowA..+63) and B (rows rowB..+63), k-major ----
        #pragma unroll
        for (int rr = 0; rr < BM; rr += 16) {
            float4 av = *(const float4*)&x[(size_t)(rowA + lr + rr) * D_DIM + kb + lk];
            float4 bv = *(const float4*)&x[(size_t)(rowB + lr + rr) * D_DIM + kb + lk];
            As[lk + 0][lr + rr] = av.x;
            As[lk + 1][lr + rr] = av.y;
            As[lk + 2][lr + rr] = av.z;
            As[lk + 3][lr + rr] = av.w;
            Bs[lk + 0][lr + rr] = bv.x;
            Bs[lk + 1][lr + rr] = bv.y;
            Bs[lk + 2][lr + rr] = bv.z;
            Bs[lk + 3][lr + rr] = bv.w;
        }
        __syncthreads();

        // ---- accumulate |a - b| over this k-chunk ----
        #pragma unroll 4
        for (int k = 0; k < BK; ++k) {
            float a0 = As[k][ty * 4 + 0];
            float a1 = As[k][ty * 4 + 1];
            float a2 = As[k][ty * 4 + 2];
            float a3 = As[k][ty * 4 + 3];
            float b0 = Bs[k][tx * 4 + 0];
            float b1 = Bs[k][tx * 4 + 1];
            float b2 = Bs[k][tx * 4 + 2];
            float b3 = Bs[k][tx * 4 + 3];

            acc[0][0] += fabsf(a0 - b0); acc[0][1] += fabsf(a0 - b1);
            acc[0][2] += fabsf(a0 - b2); acc[0][3] += fabsf(a0 - b3);
            acc[1][0] += fabsf(a1 - b0); acc[1][1] += fabsf(a1 - b1);
            acc[1][2] += fabsf(a1 - b2); acc[1][3] += fabsf(a1 - b3);
            acc[2][0] += fabsf(a2 - b0); acc[2][1] += fabsf(a2 - b1);
            acc[2][2] += fabsf(a2 - b2); acc[2][3] += fabsf(a2 - b3);
            acc[3][0] += fabsf(a3 - b0); acc[3][1] += fabsf(a3 - b1);
            acc[3][2] += fabsf(a3 - b2); acc[3][3] += fabsf(a3 - b3);
        }
        __syncthreads();
    }

    // ---- epilogue: out[i, 512 + j], coalesced float4 per row ----
    #pragma unroll
    for (int r = 0; r < 4; ++r) {
        float4 o = make_float4(acc[r][0], acc[r][1], acc[r][2], acc[r][3]);
        *(float4*)&out[(size_t)(rowA + ty * 4 + r) * OUTW + D_DIM + rowB + tx * 4] = o;
    }
}

extern "C" void kernel_launch(void* const* d_in, const int* in_sizes, int n_in,
                              void* d_out, int out_size, void* d_ws, size_t ws_size,
                              hipStream_t stream) {
    const float* x   = (const float*)d_in[0];
    float*       out = (float*)d_out;

    // copy inputs into out[:, 0:512]: N*D/4 = 131072 float4 -> 512 blocks x 256
    hipLaunchKernelGGL(copy_rows_kernel, dim3((N_PTS * D_DIM / 4) / 256), dim3(256),
                       0, stream, x, out);

    // all-pairs L1: 16x16 tiles of 64x64
    hipLaunchKernelGGL(l1_pairs_kernel, dim3(N_PTS / BN, N_PTS / BM), dim3(16, 16),
                       0, stream, x, out);
}

// Round 2
// 49.543 us; speedup vs baseline: 1.1524x; 1.1524x over previous
//
#include <hip/hip_runtime.h>

// MinibatchDiscrimination — all-pairs L1 distance + concat.
//   inputs: [N=1024, D=512] fp32
//   out[i, 0:512]   = inputs[i, :]
//   out[i, 512 + j] = sum_d |x[i,d] - x[j,d]|
// out is [1024, 1536] fp32 row-major.
//
// R2 design: 64x64 output tile per block, 1024 threads = 4 k-groups x 256.
// Each group owns 128 of the 512 k's with private LDS tiles (k-major,
// stride 68 so fragment reads are 16B-aligned ds_read_b128). Cross-group
// register partials reduced through LDS at the end. 16 waves/CU = 4/SIMD.

#define N_PTS 1024
#define D_DIM 512
#define OUTW  (D_DIM + N_PTS)   // 1536

#define BM 64
#define BN 64
#define BK 64
#define NG 4                     // k-split groups per block
#define LSTR 68                  // LDS row stride (mult of 4 -> aligned b128 reads)

// -------- copy inputs into out[:, 0:D] ------------------------------------
__global__ __launch_bounds__(256) void copy_rows_kernel(const float* __restrict__ x,
                                                        float* __restrict__ out) {
    int idx = blockIdx.x * blockDim.x + threadIdx.x;   // 0 .. N*D/4-1
    int i = idx >> 7;          // D/4 = 128 float4 per row
    int d = idx & 127;
    *(float4*)&out[(size_t)i * OUTW + (d << 2)] =
        *(const float4*)&x[(size_t)i * D_DIM + (d << 2)];
}

// -------- tiled all-pairs L1 with in-block k-split -------------------------
__global__ __launch_bounds__(1024, 4) void l1_pairs_kernel(const float* __restrict__ x,
                                                           float* __restrict__ out) {
    __shared__ float As[NG][BK][LSTR];   // k-major: As[g][k][i], 69.6KB
    __shared__ float Bs[NG][BK][LSTR];   // total 139.3KB < 160KB

    const int t  = threadIdx.x;
    const int z  = t >> 8;          // k-group 0..3
    const int tg = t & 255;         // thread-in-group
    const int tx = tg & 15;         // j-fragment
    const int ty = tg >> 4;         // i-fragment
    const int lr = tg >> 4;         // staging: row 0..15
    const int lk = (tg & 15) << 2;  // staging: k-col (float4)

    const int rowA = blockIdx.y * BM;
    const int rowB = blockIdx.x * BN;

    float acc[4][4] = {};

    // each group covers k in [z*128, z*128+128), two BK=64 chunks
    #pragma unroll
    for (int kb = 0; kb < D_DIM / NG; kb += BK) {
        const int k0 = z * (D_DIM / NG) + kb;

        #pragma unroll
        for (int rr = 0; rr < BM; rr += 16) {
            float4 av = *(const float4*)&x[(size_t)(rowA + lr + rr) * D_DIM + k0 + lk];
            float4 bv = *(const float4*)&x[(size_t)(rowB + lr + rr) * D_DIM + k0 + lk];
            As[z][lk + 0][lr + rr] = av.x;
            As[z][lk + 1][lr + rr] = av.y;
            As[z][lk + 2][lr + rr] = av.z;
            As[z][lk + 3][lr + rr] = av.w;
            Bs[z][lk + 0][lr + rr] = bv.x;
            Bs[z][lk + 1][lr + rr] = bv.y;
            Bs[z][lk + 2][lr + rr] = bv.z;
            Bs[z][lk + 3][lr + rr] = bv.w;
        }
        __syncthreads();

        #pragma unroll 4
        for (int k = 0; k < BK; ++k) {
            float4 a = *(const float4*)&As[z][k][ty << 2];   // aligned b128, broadcast
            float4 b = *(const float4*)&Bs[z][k][tx << 2];   // aligned b128, 2-way (free)

            acc[0][0] += fabsf(a.x - b.x); acc[0][1] += fabsf(a.x - b.y);
            acc[0][2] += fabsf(a.x - b.z); acc[0][3] += fabsf(a.x - b.w);
            acc[1][0] += fabsf(a.y - b.x); acc[1][1] += fabsf(a.y - b.y);
            acc[1][2] += fabsf(a.y - b.z); acc[1][3] += fabsf(a.y - b.w);
            acc[2][0] += fabsf(a.z - b.x); acc[2][1] += fabsf(a.z - b.y);
            acc[2][2] += fabsf(a.z - b.z); acc[2][3] += fabsf(a.z - b.w);
            acc[3][0] += fabsf(a.w - b.x); acc[3][1] += fabsf(a.w - b.y);
            acc[3][2] += fabsf(a.w - b.z); acc[3][3] += fabsf(a.w - b.w);
        }
        __syncthreads();
    }

    // ---- cross-group reduction through LDS (reuse As region) ----
    // slot stride 20 floats (80B: 16B-aligned, bank-rotating)
    float* red = &As[0][0][0];   // need 3*256*20*4B = 61.4KB < 66.5KB (As alone)
    if (z != 0) {
        float* p = &red[(size_t)((z - 1) * 256 + tg) * 20];
        *(float4*)&p[0]  = make_float4(acc[0][0], acc[0][1], acc[0][2], acc[0][3]);
        *(float4*)&p[4]  = make_float4(acc[1][0], acc[1][1], acc[1][2], acc[1][3]);
        *(float4*)&p[8]  = make_float4(acc[2][0], acc[2][1], acc[2][2], acc[2][3]);
        *(float4*)&p[12] = make_float4(acc[3][0], acc[3][1], acc[3][2], acc[3][3]);
    }
    __syncthreads();
    if (z == 0) {
        #pragma unroll
        for (int q = 0; q < 3; ++q) {
            const float* p = &red[(size_t)(q * 256 + tg) * 20];
            #pragma unroll
            for (int r = 0; r < 4; ++r) {
                float4 v = *(const float4*)&p[r * 4];
                acc[r][0] += v.x; acc[r][1] += v.y; acc[r][2] += v.z; acc[r][3] += v.w;
            }
        }
        #pragma unroll
        for (int r = 0; r < 4; ++r) {
            float4 o = make_float4(acc[r][0], acc[r][1], acc[r][2], acc[r][3]);
            *(float4*)&out[(size_t)(rowA + (ty << 2) + r) * OUTW + D_DIM + rowB + (tx << 2)] = o;
        }
    }
}

extern "C" void kernel_launch(void* const* d_in, const int* in_sizes, int n_in,
                              void* d_out, int out_size, void* d_ws, size_t ws_size,
                              hipStream_t stream) {
    const float* x   = (const float*)d_in[0];
    float*       out = (float*)d_out;

    hipLaunchKernelGGL(copy_rows_kernel, dim3((N_PTS * D_DIM / 4) / 256), dim3(256),
                       0, stream, x, out);

    hipLaunchKernelGGL(l1_pairs_kernel, dim3(N_PTS / BN, N_PTS / BM), dim3(1024),
                       0, stream, x, out);
}